// Round 17
// baseline (1980.038 us; speedup 1.0000x reference)
//
#include <hip/hip_runtime.h>
#include <stdint.h>

namespace {

constexpr int NIN = 21;
constexpr int T   = 3000;
constexpr int NB  = 2;     // batches per block -> 256 blocks = 1 per CU

typedef _Float16 f16x8 __attribute__((ext_vector_type(8)));
typedef float    f32x4 __attribute__((ext_vector_type(4)));

__device__ __forceinline__ float frcp(float x){ return __builtin_amdgcn_rcpf(x); }
__device__ __forceinline__ float sigm(float v){ return frcp(1.0f + __expf(-v)); }
__device__ __forceinline__ float tanh_fast(float v){
    return fmaf(-2.0f, frcp(__expf(2.0f*v) + 1.0f), 1.0f);
}

template<int CTRL>
__device__ __forceinline__ float dppf(float v){
    return __int_as_float(__builtin_amdgcn_update_dpp(
        0, __float_as_int(v), CTRL, 0xF, 0xF, true));
}
// Verified family: row_ror:J => out[i] = in[(i-J)&15]; row_shr:N => out[i] = in[i-N]
constexpr int SHR4  = 0x114;
constexpr int SHR8  = 0x118;
constexpr int SHR12 = 0x11C;
constexpr int ROR14 = 0x12E;   // out[i] = in[(i+2)&15]

#define MFMA(A,B,C) __builtin_amdgcn_mfma_f32_16x16x32_f16((A),(B),(C),0,0,0)

__device__ __forceinline__ f16x8 ldfrag(const _Float16* p){
    return *reinterpret_cast<const f16x8*>(p);   // aligned 16B LDS read
}
__device__ __forceinline__ void cvt8h(const float* s, f16x8& hi){
    #pragma unroll
    for (int j=0;j<8;++j) hi[j] = (_Float16)s[j];
}

// Verified MFMA layout (r8-r16): D[n][m] = sum_k A[n][k]*B[m][k]
//   A-frag: n = lane&15, k = 32*kc + 8*(lane>>4) + j ; B same
//   D:      m = lane&15, n = 4*(lane>>4) + v
// B cols: 0,1 = batch0/1 Hhi; 2,3 = batch0/1 Hlo; >=4 zero.
// W f16 hi-only; gate = D[:,m] + D[:,m+2] = Whi·(Hhi+Hlo). Bias halved in C-init.
__device__ __forceinline__ void spread_fold(const f32x4& a0, const f32x4& a1,
                                            const f32x4& a2, const f32x4& a3,
                                            int q, float& g0, float& g1,
                                            float& g2, float& g3){
    float u1,u2,u3;
    u1=dppf<SHR4>(a0[1]); u2=dppf<SHR8>(a0[2]); u3=dppf<SHR12>(a0[3]);
    g0=(q==0)?a0[0]:(q==1)?u1:(q==2)?u2:u3;
    u1=dppf<SHR4>(a1[1]); u2=dppf<SHR8>(a1[2]); u3=dppf<SHR12>(a1[3]);
    g1=(q==0)?a1[0]:(q==1)?u1:(q==2)?u2:u3;
    u1=dppf<SHR4>(a2[1]); u2=dppf<SHR8>(a2[2]); u3=dppf<SHR12>(a2[3]);
    g2=(q==0)?a2[0]:(q==1)?u1:(q==2)?u2:u3;
    u1=dppf<SHR4>(a3[1]); u2=dppf<SHR8>(a3[2]); u3=dppf<SHR12>(a3[3]);
    g3=(q==0)?a3[0]:(q==1)?u1:(q==2)?u2:u3;
    g0 += dppf<ROR14>(g0);
    g1 += dppf<ROR14>(g1);
    g2 += dppf<ROR14>(g2);
    g3 += dppf<ROR14>(g3);
}

// Anti-phased schedule (this round):
//   S1: L0 MFMA(t)+glue(t)         | L1 glue of step t-2 (acc from regs)
//   BW ; S2: writes h1(t), h2(t-2), x(t+2) ; BR
//   S3: fragment reads             | L1 MFMA(step t-1) -> acc regs
// All LDS reads in S3, all writes in S2, two barriers between -> race-free
// for any <=1-segment wave drift (r13/r16 discipline preserved).
__launch_bounds__(512, 2)
__global__ void lstm_mf8(const float* __restrict__ x,
                         const float* __restrict__ Wih0, const float* __restrict__ Whh0,
                         const float* __restrict__ bih0, const float* __restrict__ bhh0,
                         const float* __restrict__ Wih1, const float* __restrict__ Whh1,
                         const float* __restrict__ bih1, const float* __restrict__ bhh1,
                         const float* __restrict__ Wfc,  const float* __restrict__ bfc,
                         float* __restrict__ out)
{
    const int tid  = threadIdx.x;
    const int lane = tid & 63;
    const int wid  = tid >> 6;
    const int c    = lane >> 4;     // k-subchunk 0..3
    const int mcol = lane & 15;
    const int b0   = blockIdx.x * NB;
    const bool isL0 = (wid < 4);
    const int  w    = wid & 3;      // unit range [16w, 16w+16)

    __shared__ __align__(16) _Float16 h1p[2][2][NB][72]; // [buf][plane][batch][unit(+pad)]
    __shared__ __align__(16) _Float16 h2p[2][2][NB][72];
    __shared__ __align__(16) _Float16 xp [4][2][NB][40]; // [slot][plane][batch][feat(+pad)]

    // ----- weights: unified slots shared by roles (hi plane only) -----
    f16x8 Whi[4][4];
    f32x4 bias4[4];
    {
        float tmp[8];
        #pragma unroll
        for (int tau = 0; tau < 4; ++tau) {
            const int n = 64*tau + 16*w + mcol;
            if (isL0) {
                #pragma unroll
                for (int j=0;j<8;++j){ int k=8*c+j; tmp[j] = (k<NIN)? Wih0[n*NIN+k] : 0.0f; }
                cvt8h(tmp, Whi[tau][0]);
                #pragma unroll
                for (int kc=0;kc<2;++kc){
                    #pragma unroll
                    for (int j=0;j<8;++j) tmp[j] = Whh0[n*64 + 32*kc + 8*c + j];
                    cvt8h(tmp, Whi[tau][1+kc]);
                }
                #pragma unroll
                for (int j=0;j<8;++j) Whi[tau][3][j] = (_Float16)0.f;
            } else {
                #pragma unroll
                for (int kc=0;kc<2;++kc){
                    #pragma unroll
                    for (int j=0;j<8;++j) tmp[j] = Wih1[n*64 + 32*kc + 8*c + j];
                    cvt8h(tmp, Whi[tau][kc]);
                }
                #pragma unroll
                for (int kc=0;kc<2;++kc){
                    #pragma unroll
                    for (int j=0;j<8;++j) tmp[j] = Whh1[n*64 + 32*kc + 8*c + j];
                    cvt8h(tmp, Whi[tau][2+kc]);
                }
            }
            const int nb = 64*tau + 16*w + 4*c;
            #pragma unroll
            for (int v=0; v<4; ++v)
                bias4[tau][v] = 0.5f * (isL0 ? (bih0[nb+v] + bhh0[nb+v])
                                             : (bih1[nb+v] + bhh1[nb+v]));
        }
    }

    // ----- LDS zero init -----
    {
        uint32_t* p1 = (uint32_t*)&h1p[0][0][0][0];   // 288 u32
        uint32_t* p2 = (uint32_t*)&h2p[0][0][0][0];
        uint32_t* p3 = (uint32_t*)&xp[0][0][0][0];    // 320 u32
        if (tid < 288){ p1[tid]=0u; p2[tid]=0u; }
        if (tid < 320){ p3[tid]=0u; }
    }
    __syncthreads();

    // ----- x staging: waves 0,1, lane<NIN -> (batch=wid, feat=lane) -----
    const bool stg = (wid < 2) && (lane < NIN);
    const float* xsrc = x + (size_t)(b0 + (wid & 1)) * T * NIN + lane;
    float xrA = 0.f, xrB = 0.f;
    if (stg){
        float x0 = xsrc[0], x1 = xsrc[NIN];
        _Float16 hh0 = (_Float16)x0;
        xp[0][0][wid][lane] = hh0;
        xp[0][1][wid][lane] = (_Float16)(x0 - (float)hh0);
        _Float16 hh1 = (_Float16)x1;
        xp[1][0][wid][lane] = hh1;
        xp[1][1][wid][lane] = (_Float16)(x1 - (float)hh1);
        xrA = xsrc[(size_t)2*NIN];
        xrB = xsrc[(size_t)3*NIN];
    }
    __syncthreads();

    // ----- B fragments: lane mcol<4 -> batch = mcol&1, plane = mcol>>1 -----
    f16x8 Bf[4];
    #pragma unroll
    for (int kc=0;kc<4;++kc)
        #pragma unroll
        for (int j=0;j<8;++j) Bf[kc][j] = (_Float16)0.f;
    if (isL0 && mcol < 4){
        Bf[0] = ldfrag(&xp[0][mcol>>1][mcol&1][8*c]);   // x(0); h slots stay 0
    }

    float cst = 0.f;
    const int q   = mcol >> 2;
    const int m   = mcol & 1;
    const int pl  = (mcol >> 1) & 1;
    const int u   = 16*w + 4*c + q;
    const bool pw = ((mcol & 2) == 0);

    f32x4 ac0 = {0,0,0,0}, ac1 = {0,0,0,0}, ac2 = {0,0,0,0}, ac3 = {0,0,0,0};

    // ====== main loop: 750 x 4 phases; t = tb+ph in [0, T) ======
    for (int tb = 0; tb < T; tb += 4) {
        #pragma unroll
        for (int ph = 0; ph < 4; ++ph) {
            const int t = tb + ph;
            float xnew = 0.f;
            _Float16 hh = (_Float16)0.f, hl = (_Float16)0.f;
            bool dow = false;

            // ---------------- S1 ----------------
            if (isL0) {
                if (stg && (t + 4 < T)) xnew = xsrc[(size_t)(t+4)*NIN];
                // MFMA(t): L0 kc=0..2, bias as C-init of first chain-op
                f32x4 a0 = MFMA(Whi[0][0], Bf[0], bias4[0]);
                f32x4 a1 = MFMA(Whi[1][0], Bf[0], bias4[1]);
                f32x4 a2 = MFMA(Whi[2][0], Bf[0], bias4[2]);
                f32x4 a3 = MFMA(Whi[3][0], Bf[0], bias4[3]);
                #pragma unroll
                for (int kc=1; kc<3; ++kc){
                    a0 = MFMA(Whi[0][kc], Bf[kc], a0);
                    a1 = MFMA(Whi[1][kc], Bf[kc], a1);
                    a2 = MFMA(Whi[2][kc], Bf[kc], a2);
                    a3 = MFMA(Whi[3][kc], Bf[kc], a3);
                }
                float g0,g1,g2,g3;
                spread_fold(a0,a1,a2,a3,q,g0,g1,g2,g3);
                if (pw) {
                    float i_ = sigm(g0), f_ = sigm(g1);
                    float gg = tanh_fast(g2), o_ = sigm(g3);
                    cst = fmaf(f_, cst, i_ * gg);
                    float h = o_ * tanh_fast(cst);
                    hh = (_Float16)h;
                    hl = (_Float16)(h - (float)hh);
                    dow = true;
                }
            } else {
                if (t >= 2) {       // glue for L1 step t-2 (acc from S3 of phase t-1)
                    float g0,g1,g2,g3;
                    spread_fold(ac0,ac1,ac2,ac3,q,g0,g1,g2,g3);
                    if (pw) {
                        float i_ = sigm(g0), f_ = sigm(g1);
                        float gg = tanh_fast(g2), o_ = sigm(g3);
                        cst = fmaf(f_, cst, i_ * gg);
                        float h = o_ * tanh_fast(cst);
                        hh = (_Float16)h;
                        hl = (_Float16)(h - (float)hh);
                        dow = true;
                    }
                }
            }

            __syncthreads();   // BW: all S3 reads of phase t-1 completed

            // ---------------- S2: writes ----------------
            if (isL0) {
                if (dow) {
                    h1p[ph & 1][0][m][u] = hh;     // h1(t), slot t&1
                    h1p[ph & 1][1][m][u] = hl;
                }
                if (stg){
                    if (t + 2 < T){
                        _Float16 xh = (_Float16)xrA;
                        xp[(ph+2) & 3][0][wid][lane] = xh;
                        xp[(ph+2) & 3][1][wid][lane] = (_Float16)(xrA - (float)xh);
                    }
                    xrA = xrB; xrB = xnew;
                }
            } else if (dow) {
                h2p[ph & 1][0][m][u] = hh;         // h2(t-2), slot (t-2)&1 = t&1
                h2p[ph & 1][1][m][u] = hl;
            }

            __syncthreads();   // BR: writes visible

            // ---------------- S3: fragment reads (+ L1 MFMA step t-1) --------
            if (mcol < 4){
                if (isL0){
                    Bf[0] = ldfrag(&xp[(ph+1) & 3][pl][m][8*c]);        // x(t+1)
                    Bf[1] = ldfrag(&h1p[ph & 1][pl][m][8*c]);           // h1(t)
                    Bf[2] = ldfrag(&h1p[ph & 1][pl][m][32 + 8*c]);
                } else {
                    Bf[0] = ldfrag(&h1p[(ph+1) & 1][pl][m][8*c]);       // h1(t-1)
                    Bf[1] = ldfrag(&h1p[(ph+1) & 1][pl][m][32 + 8*c]);
                    Bf[2] = ldfrag(&h2p[ph & 1][pl][m][8*c]);           // h2(t-2)
                    Bf[3] = ldfrag(&h2p[ph & 1][pl][m][32 + 8*c]);
                }
            }
            if (!isL0) {
                // MFMA for L1 step t-1 (t=0: reads zero slots, acc unconsumed)
                ac0 = MFMA(Whi[0][0], Bf[0], bias4[0]);
                ac1 = MFMA(Whi[1][0], Bf[0], bias4[1]);
                ac2 = MFMA(Whi[2][0], Bf[0], bias4[2]);
                ac3 = MFMA(Whi[3][0], Bf[0], bias4[3]);
                #pragma unroll
                for (int kc=1; kc<4; ++kc){
                    ac0 = MFMA(Whi[0][kc], Bf[kc], ac0);
                    ac1 = MFMA(Whi[1][kc], Bf[kc], ac1);
                    ac2 = MFMA(Whi[2][kc], Bf[kc], ac2);
                    ac3 = MFMA(Whi[3][kc], Bf[kc], ac3);
                }
            }
        }
    }

    // ====== epilogue tau=3000: L1 glue(2998) + MFMA(2999) ======
    {
        _Float16 hh = (_Float16)0.f, hl = (_Float16)0.f;
        bool dow = false;
        if (!isL0) {
            float g0,g1,g2,g3;
            spread_fold(ac0,ac1,ac2,ac3,q,g0,g1,g2,g3);
            if (pw) {
                float i_ = sigm(g0), f_ = sigm(g1);
                float gg = tanh_fast(g2), o_ = sigm(g3);
                cst = fmaf(f_, cst, i_ * gg);
                float h = o_ * tanh_fast(cst);
                hh = (_Float16)h;
                hl = (_Float16)(h - (float)hh);
                dow = true;
            }
        }
        __syncthreads();   // BW
        if (!isL0 && dow){
            h2p[0][0][m][u] = hh;      // h2(2998), slot 2998&1 = 0
            h2p[0][1][m][u] = hl;
        }
        __syncthreads();   // BR
        if (!isL0 && mcol < 4){
            Bf[0] = ldfrag(&h1p[1][pl][m][8*c]);        // h1(2999), slot 1
            Bf[1] = ldfrag(&h1p[1][pl][m][32 + 8*c]);
            Bf[2] = ldfrag(&h2p[0][pl][m][8*c]);        // h2(2998)
            Bf[3] = ldfrag(&h2p[0][pl][m][32 + 8*c]);
        }
        if (!isL0) {
            ac0 = MFMA(Whi[0][0], Bf[0], bias4[0]);
            ac1 = MFMA(Whi[1][0], Bf[0], bias4[1]);
            ac2 = MFMA(Whi[2][0], Bf[0], bias4[2]);
            ac3 = MFMA(Whi[3][0], Bf[0], bias4[3]);
            #pragma unroll
            for (int kc=1; kc<4; ++kc){
                ac0 = MFMA(Whi[0][kc], Bf[kc], ac0);
                ac1 = MFMA(Whi[1][kc], Bf[kc], ac1);
                ac2 = MFMA(Whi[2][kc], Bf[kc], ac2);
                ac3 = MFMA(Whi[3][kc], Bf[kc], ac3);
            }
        }
    }
    // ====== epilogue tau=3001: L1 glue(2999) ======
    if (!isL0) {
        float g0,g1,g2,g3;
        spread_fold(ac0,ac1,ac2,ac3,q,g0,g1,g2,g3);
        if (pw) {
            float i_ = sigm(g0), f_ = sigm(g1);
            float gg = tanh_fast(g2), o_ = sigm(g3);
            cst = fmaf(f_, cst, i_ * gg);
            float h = o_ * tanh_fast(cst);
            _Float16 hh = (_Float16)h;
            h2p[1][0][m][u] = hh;      // h2(2999), slot 2999&1 = 1
            h2p[1][1][m][u] = (_Float16)(h - (float)hh);
        }
    }
    __syncthreads();

    // ---------------- FC epilogue: out[b] = dot(h2(T-1), Wfc) + bfc ----------
    if (wid < NB) {
        float hv = (float)h2p[(T-1) & 1][0][wid][lane]
                 + (float)h2p[(T-1) & 1][1][wid][lane];
        float val = hv * Wfc[lane];
        #pragma unroll
        for (int off = 32; off > 0; off >>= 1)
            val += __shfl_down(val, off, 64);
        if (lane == 0) out[b0 + wid] = val + bfc[0];
    }
}

} // namespace

extern "C" void kernel_launch(void* const* d_in, const int* in_sizes, int n_in,
                              void* d_out, int out_size, void* d_ws, size_t ws_size,
                              hipStream_t stream)
{
    const float* x    = (const float*)d_in[0];
    const float* Wih0 = (const float*)d_in[1];
    const float* Whh0 = (const float*)d_in[2];
    const float* bih0 = (const float*)d_in[3];
    const float* bhh0 = (const float*)d_in[4];
    const float* Wih1 = (const float*)d_in[5];
    const float* Whh1 = (const float*)d_in[6];
    const float* bih1 = (const float*)d_in[7];
    const float* bhh1 = (const float*)d_in[8];
    const float* Wfc  = (const float*)d_in[9];
    const float* bfc  = (const float*)d_in[10];
    float* out = (float*)d_out;

    hipLaunchKernelGGL(lstm_mf8, dim3(512 / NB), dim3(512), 0, stream,
                       x, Wih0, Whh0, bih0, bhh0, Wih1, Whh1, bih1, bhh1,
                       Wfc, bfc, out);
}

// Round 18
// 1665.711 us; speedup vs baseline: 1.1887x; 1.1887x over previous
//
#include <hip/hip_runtime.h>
#include <stdint.h>

namespace {

constexpr int NIN = 21;
constexpr int T   = 3000;
constexpr int NB  = 2;     // batches per block -> 256 blocks = 1 per CU

typedef _Float16 f16x8 __attribute__((ext_vector_type(8)));
typedef float    f32x4 __attribute__((ext_vector_type(4)));

__device__ __forceinline__ float frcp(float x){ return __builtin_amdgcn_rcpf(x); }
__device__ __forceinline__ float sigm(float v){ return frcp(1.0f + __expf(-v)); }
__device__ __forceinline__ float tanh_fast(float v){
    return fmaf(-2.0f, frcp(__expf(2.0f*v) + 1.0f), 1.0f);
}

template<int CTRL>
__device__ __forceinline__ float dppf(float v){
    return __int_as_float(__builtin_amdgcn_update_dpp(
        0, __float_as_int(v), CTRL, 0xF, 0xF, true));
}
// Verified family: row_ror:J => out[i] = in[(i-J)&15]; row_shr:N => out[i] = in[i-N]
constexpr int SHR4  = 0x114;
constexpr int SHR8  = 0x118;
constexpr int SHR12 = 0x11C;
constexpr int ROR14 = 0x12E;   // out[i] = in[(i+2)&15]

#define MFMA(A,B,C) __builtin_amdgcn_mfma_f32_16x16x32_f16((A),(B),(C),0,0,0)

// LDS-visibility barrier WITHOUT vmcnt drain: ds ops retired, then barrier.
// (__syncthreads would add s_waitcnt vmcnt(0), draining in-flight x prefetch.)
#define LDS_BARRIER() asm volatile("s_waitcnt lgkmcnt(0)\n\ts_barrier" ::: "memory")

__device__ __forceinline__ f16x8 ldfrag(const _Float16* p){
    return *reinterpret_cast<const f16x8*>(p);   // aligned 16B LDS read
}
__device__ __forceinline__ void cvt8h(const float* s, f16x8& hi){
    #pragma unroll
    for (int j=0;j<8;++j) hi[j] = (_Float16)s[j];
}

// Verified MFMA layout (r8-r16): D[n][m] = sum_k A[n][k]*B[m][k]
//   A-frag: n = lane&15, k = 32*kc + 8*(lane>>4) + j ; B same
//   D:      m = lane&15, n = 4*(lane>>4) + v
// B cols: 0,1 = batch0/1 Hhi; 2,3 = batch0/1 Hlo; >=4 zero.
// W f16 hi-only; gate = D[:,m] + D[:,m+2] = Whi·(Hhi+Hlo). Bias halved in C-init.
__device__ __forceinline__ void spread_fold(const f32x4& a0, const f32x4& a1,
                                            const f32x4& a2, const f32x4& a3,
                                            int q, float& g0, float& g1,
                                            float& g2, float& g3){
    float u1,u2,u3;
    u1=dppf<SHR4>(a0[1]); u2=dppf<SHR8>(a0[2]); u3=dppf<SHR12>(a0[3]);
    g0=(q==0)?a0[0]:(q==1)?u1:(q==2)?u2:u3;
    u1=dppf<SHR4>(a1[1]); u2=dppf<SHR8>(a1[2]); u3=dppf<SHR12>(a1[3]);
    g1=(q==0)?a1[0]:(q==1)?u1:(q==2)?u2:u3;
    u1=dppf<SHR4>(a2[1]); u2=dppf<SHR8>(a2[2]); u3=dppf<SHR12>(a2[3]);
    g2=(q==0)?a2[0]:(q==1)?u1:(q==2)?u2:u3;
    u1=dppf<SHR4>(a3[1]); u2=dppf<SHR8>(a3[2]); u3=dppf<SHR12>(a3[3]);
    g3=(q==0)?a3[0]:(q==1)?u1:(q==2)?u2:u3;
    g0 += dppf<ROR14>(g0);
    g1 += dppf<ROR14>(g1);
    g2 += dppf<ROR14>(g2);
    g3 += dppf<ROR14>(g3);
}

// Single-barrier schedule, 4-deep buffers. Per step t (r16 lockstep roles:
// L0 computes h1(t), L1 computes h2(t-1)):
//   S1: MFMA + spread + pointwise (register-only; issue x(t+4) load)
//   S2: writes h1(t)->slot t&3, h2(t-1)->slot (t-1)&3, x(t+2)->slot (t+2)&3
//   LDS_BARRIER
//   S3: reads h1(t), x(t+1), h2(t-1) fragments
// Conflict audit (read@S3(t) vs next write of same slot): h1 slot t&3 ->
// S2(t+4) (3 barriers later); h2 slot (t-1)&3 -> S2(t+4); x slot (t+1)&3 ->
// S2(t+3). All >=1 full barrier after the read => race-free for any drift.
__launch_bounds__(512, 2)
__global__ void lstm_mf9(const float* __restrict__ x,
                         const float* __restrict__ Wih0, const float* __restrict__ Whh0,
                         const float* __restrict__ bih0, const float* __restrict__ bhh0,
                         const float* __restrict__ Wih1, const float* __restrict__ Whh1,
                         const float* __restrict__ bih1, const float* __restrict__ bhh1,
                         const float* __restrict__ Wfc,  const float* __restrict__ bfc,
                         float* __restrict__ out)
{
    const int tid  = threadIdx.x;
    const int lane = tid & 63;
    const int wid  = tid >> 6;
    const int c    = lane >> 4;     // k-subchunk 0..3
    const int mcol = lane & 15;
    const int b0   = blockIdx.x * NB;
    const bool isL0 = (wid < 4);
    const int  w    = wid & 3;      // unit range [16w, 16w+16)

    __shared__ __align__(16) _Float16 h1p[4][2][NB][72]; // [slot][plane][batch][unit(+pad)]
    __shared__ __align__(16) _Float16 h2p[4][2][NB][72];
    __shared__ __align__(16) _Float16 xp [4][2][NB][40]; // [slot][plane][batch][feat(+pad)]

    // ----- weights: unified slots shared by roles (hi plane only) -----
    f16x8 Whi[4][4];
    f32x4 bias4[4];
    {
        float tmp[8];
        #pragma unroll
        for (int tau = 0; tau < 4; ++tau) {
            const int n = 64*tau + 16*w + mcol;
            if (isL0) {
                #pragma unroll
                for (int j=0;j<8;++j){ int k=8*c+j; tmp[j] = (k<NIN)? Wih0[n*NIN+k] : 0.0f; }
                cvt8h(tmp, Whi[tau][0]);
                #pragma unroll
                for (int kc=0;kc<2;++kc){
                    #pragma unroll
                    for (int j=0;j<8;++j) tmp[j] = Whh0[n*64 + 32*kc + 8*c + j];
                    cvt8h(tmp, Whi[tau][1+kc]);
                }
                #pragma unroll
                for (int j=0;j<8;++j) Whi[tau][3][j] = (_Float16)0.f;
            } else {
                #pragma unroll
                for (int kc=0;kc<2;++kc){
                    #pragma unroll
                    for (int j=0;j<8;++j) tmp[j] = Wih1[n*64 + 32*kc + 8*c + j];
                    cvt8h(tmp, Whi[tau][kc]);
                }
                #pragma unroll
                for (int kc=0;kc<2;++kc){
                    #pragma unroll
                    for (int j=0;j<8;++j) tmp[j] = Whh1[n*64 + 32*kc + 8*c + j];
                    cvt8h(tmp, Whi[tau][2+kc]);
                }
            }
            const int nb = 64*tau + 16*w + 4*c;
            #pragma unroll
            for (int v=0; v<4; ++v)
                bias4[tau][v] = 0.5f * (isL0 ? (bih0[nb+v] + bhh0[nb+v])
                                             : (bih1[nb+v] + bhh1[nb+v]));
        }
    }

    // ----- LDS zero init (all 4 slots; slots 3/(t-1) double as zero states) -----
    {
        uint32_t* p1 = (uint32_t*)&h1p[0][0][0][0];   // 2304B = 576 u32
        uint32_t* p2 = (uint32_t*)&h2p[0][0][0][0];
        uint32_t* p3 = (uint32_t*)&xp[0][0][0][0];    // 1280B = 320 u32
        for (int i = tid; i < 576; i += 512){ p1[i]=0u; p2[i]=0u; }
        if (tid < 320) p3[tid] = 0u;
    }
    __syncthreads();

    // ----- x staging: waves 0,1, lane<NIN -> (batch=wid, feat=lane) -----
    const bool stg = (wid < 2) && (lane < NIN);
    const float* xsrc = x + (size_t)(b0 + (wid & 1)) * T * NIN + lane;
    // static prefetch regs: xq[p] holds x loaded at phase p (= x(p+4) in steady
    // state); consumed (LDS write) 2 phases later -> vmcnt wait deferred.
    float xq0 = 0.f, xq1 = 0.f, xq2 = 0.f, xq3 = 0.f;
    if (stg){
        float x0 = xsrc[0], x1 = xsrc[NIN];
        _Float16 hh0 = (_Float16)x0;
        xp[0][0][wid][lane] = hh0;
        xp[0][1][wid][lane] = (_Float16)(x0 - (float)hh0);
        _Float16 hh1 = (_Float16)x1;
        xp[1][0][wid][lane] = hh1;
        xp[1][1][wid][lane] = (_Float16)(x1 - (float)hh1);
        xq2 = xsrc[(size_t)2*NIN];   // consumed at t=0 (writes x(2))
        xq3 = xsrc[(size_t)3*NIN];   // consumed at t=1 (writes x(3))
    }
    __syncthreads();

    // ----- B fragments: lane mcol<4 -> batch = mcol&1, plane = mcol>>1 -----
    f16x8 Bf[4];
    #pragma unroll
    for (int kc=0;kc<4;++kc)
        #pragma unroll
        for (int j=0;j<8;++j) Bf[kc][j] = (_Float16)0.f;
    if (isL0 && mcol < 4){
        Bf[0] = ldfrag(&xp[0][mcol>>1][mcol&1][8*c]);   // x(0); h slots stay 0
    }

    float cst = 0.f;
    const int q   = mcol >> 2;
    const int m   = mcol & 1;
    const int pl  = (mcol >> 1) & 1;
    const int u   = 16*w + 4*c + q;
    const bool pw = ((mcol & 2) == 0);

    // ====== main loop: 750 x 4 phases; t = tb+ph in [0, T) ======
    for (int tb = 0; tb < T; tb += 4) {
        #pragma unroll
        for (int ph = 0; ph < 4; ++ph) {
            const int t = tb + ph;

            // ---- S1: issue x(t+4) load into xq[ph] (no copies; static name) --
            if (stg && (t + 4 < T)) {
                float v = xsrc[(size_t)(t+4)*NIN];
                if (ph == 0) xq0 = v; else if (ph == 1) xq1 = v;
                else if (ph == 2) xq2 = v; else xq3 = v;
            }

            // ---- S1: MFMA (Bf from S3 of prev phase) + glue ----
            f32x4 a0 = MFMA(Whi[0][0], Bf[0], bias4[0]);
            f32x4 a1 = MFMA(Whi[1][0], Bf[0], bias4[1]);
            f32x4 a2 = MFMA(Whi[2][0], Bf[0], bias4[2]);
            f32x4 a3 = MFMA(Whi[3][0], Bf[0], bias4[3]);
            #pragma unroll
            for (int kc=1; kc<3; ++kc){
                a0 = MFMA(Whi[0][kc], Bf[kc], a0);
                a1 = MFMA(Whi[1][kc], Bf[kc], a1);
                a2 = MFMA(Whi[2][kc], Bf[kc], a2);
                a3 = MFMA(Whi[3][kc], Bf[kc], a3);
            }
            if (!isL0){   // wave-uniform branch: L1 has 4th chunk
                a0 = MFMA(Whi[0][3], Bf[3], a0);
                a1 = MFMA(Whi[1][3], Bf[3], a1);
                a2 = MFMA(Whi[2][3], Bf[3], a2);
                a3 = MFMA(Whi[3][3], Bf[3], a3);
            }
            float g0,g1,g2,g3;
            spread_fold(a0,a1,a2,a3,q,g0,g1,g2,g3);

            _Float16 hh = (_Float16)0.f, hl = (_Float16)0.f;
            const bool dow = pw && (isL0 || t > 0);
            if (dow) {
                float i_ = sigm(g0), f_ = sigm(g1);
                float gg = tanh_fast(g2), o_ = sigm(g3);
                cst = fmaf(f_, cst, i_ * gg);
                float h = o_ * tanh_fast(cst);
                hh = (_Float16)h;
                hl = (_Float16)(h - (float)hh);
            }

            // ---- S2: writes ----
            if (dow) {
                if (isL0){
                    h1p[ph & 3][0][m][u] = hh;          // h1(t), slot t&3
                    h1p[ph & 3][1][m][u] = hl;
                } else {
                    h2p[(ph+3) & 3][0][m][u] = hh;      // h2(t-1), slot (t-1)&3
                    h2p[(ph+3) & 3][1][m][u] = hl;
                }
            }
            if (stg && (t + 2 < T)){
                float xv = (ph == 0) ? xq2 : (ph == 1) ? xq3
                         : (ph == 2) ? xq0 : xq1;       // xq[(ph+2)&3] = x(t+2)
                _Float16 xh = (_Float16)xv;
                xp[(ph+2) & 3][0][wid][lane] = xh;
                xp[(ph+2) & 3][1][wid][lane] = (_Float16)(xv - (float)xh);
            }

            LDS_BARRIER();   // writes visible; vmcnt NOT drained

            // ---- S3: fragment reads for step t+1 ----
            if (mcol < 4){
                if (isL0){
                    Bf[0] = ldfrag(&xp[(ph+1) & 3][pl][m][8*c]);     // x(t+1)
                    Bf[1] = ldfrag(&h1p[ph & 3][pl][m][8*c]);        // h1(t)
                    Bf[2] = ldfrag(&h1p[ph & 3][pl][m][32 + 8*c]);
                } else {
                    Bf[0] = ldfrag(&h1p[ph & 3][pl][m][8*c]);        // h1(t)
                    Bf[1] = ldfrag(&h1p[ph & 3][pl][m][32 + 8*c]);
                    Bf[2] = ldfrag(&h2p[(ph+3) & 3][pl][m][8*c]);    // h2(t-1)
                    Bf[3] = ldfrag(&h2p[(ph+3) & 3][pl][m][32 + 8*c]);
                }
            }
        }
    }

    // ====== epilogue t=T: L1 computes h2(T-1) from frags read at S3(T-1) ======
    if (!isL0) {
        f32x4 a0 = MFMA(Whi[0][0], Bf[0], bias4[0]);
        f32x4 a1 = MFMA(Whi[1][0], Bf[0], bias4[1]);
        f32x4 a2 = MFMA(Whi[2][0], Bf[0], bias4[2]);
        f32x4 a3 = MFMA(Whi[3][0], Bf[0], bias4[3]);
        #pragma unroll
        for (int kc=1; kc<4; ++kc){
            a0 = MFMA(Whi[0][kc], Bf[kc], a0);
            a1 = MFMA(Whi[1][kc], Bf[kc], a1);
            a2 = MFMA(Whi[2][kc], Bf[kc], a2);
            a3 = MFMA(Whi[3][kc], Bf[kc], a3);
        }
        float g0,g1,g2,g3;
        spread_fold(a0,a1,a2,a3,q,g0,g1,g2,g3);
        if (pw) {
            float i_ = sigm(g0), f_ = sigm(g1);
            float gg = tanh_fast(g2), o_ = sigm(g3);
            cst = fmaf(f_, cst, i_ * gg);
            float h = o_ * tanh_fast(cst);
            _Float16 hh = (_Float16)h;
            h2p[(T-1) & 3][0][m][u] = hh;      // slot 2999&3 = 3
            h2p[(T-1) & 3][1][m][u] = (_Float16)(h - (float)hh);
        }
    }
    __syncthreads();

    // ---------------- FC epilogue: out[b] = dot(h2(T-1), Wfc) + bfc ----------
    if (wid < NB) {
        float hv = (float)h2p[(T-1) & 3][0][wid][lane]
                 + (float)h2p[(T-1) & 3][1][wid][lane];
        float val = hv * Wfc[lane];
        #pragma unroll
        for (int off = 32; off > 0; off >>= 1)
            val += __shfl_down(val, off, 64);
        if (lane == 0) out[b0 + wid] = val + bfc[0];
    }
}

} // namespace

extern "C" void kernel_launch(void* const* d_in, const int* in_sizes, int n_in,
                              void* d_out, int out_size, void* d_ws, size_t ws_size,
                              hipStream_t stream)
{
    const float* x    = (const float*)d_in[0];
    const float* Wih0 = (const float*)d_in[1];
    const float* Whh0 = (const float*)d_in[2];
    const float* bih0 = (const float*)d_in[3];
    const float* bhh0 = (const float*)d_in[4];
    const float* Wih1 = (const float*)d_in[5];
    const float* Whh1 = (const float*)d_in[6];
    const float* bih1 = (const float*)d_in[7];
    const float* bhh1 = (const float*)d_in[8];
    const float* Wfc  = (const float*)d_in[9];
    const float* bfc  = (const float*)d_in[10];
    float* out = (float*)d_out;

    hipLaunchKernelGGL(lstm_mf9, dim3(512 / NB), dim3(512), 0, stream,
                       x, Wih0, Whh0, bih0, bhh0, Wih1, Whh1, bih1, bhh1,
                       Wfc, bfc, out);
}